// Round 8
// baseline (256.917 us; speedup 1.0000x reference)
//
#include <hip/hip_runtime.h>
#include <type_traits>

typedef short bf16x8 __attribute__((ext_vector_type(8)));
typedef float f32x4  __attribute__((ext_vector_type(4)));
typedef unsigned short u16;

#define MFMA(a,b,c) __builtin_amdgcn_mfma_f32_16x16x32_bf16((a),(b),(c),0,0,0)

__device__ __forceinline__ float bf2f(u16 u){ unsigned x=((unsigned)u)<<16; return __builtin_bit_cast(float,x); }
__device__ __forceinline__ u16 f2bf(float f){ unsigned x=__builtin_bit_cast(unsigned,f); x += 0x7fffu + ((x>>16)&1u); return (u16)(x>>16); }

#if __has_builtin(__builtin_amdgcn_cvt_pk_bf16_f32)
typedef __bf16 hwbf2 __attribute__((ext_vector_type(2)));
__device__ __forceinline__ unsigned pkbf(float a, float b){
  hwbf2 r = __builtin_amdgcn_cvt_pk_bf16_f32(a, b);   // lo=a, hi=b, RNE
  return __builtin_bit_cast(unsigned, r);
}
#else
__device__ __forceinline__ unsigned pkbf(float a, float b){
  unsigned ua = __builtin_bit_cast(unsigned, a), ub = __builtin_bit_cast(unsigned, b);
  ua += 0x7fffu + ((ua>>16)&1u);
  ub += 0x7fffu + ((ub>>16)&1u);
  return __builtin_amdgcn_perm(ub, ua, 0x07060302u);
}
#endif

#if __has_builtin(__builtin_amdgcn_exp2f)
#define EXP2(x) __builtin_amdgcn_exp2f(x)
#else
#define EXP2(x) exp2f(x)
#endif

__device__ __forceinline__ void async_cp16(const u16* g, u16* l){
  __builtin_amdgcn_global_load_lds((const __attribute__((address_space(1))) void*)g,
                                   (__attribute__((address_space(3))) void*)l, 16, 0, 0);
}

// ---------------- fp32 -> bf16 convert ----------------
__global__ __launch_bounds__(256) void cvt_f32_bf16(const float* __restrict__ in, u16* __restrict__ out, int n){
  int i = (blockIdx.x*256 + threadIdx.x)*4;
  if (i >= n) return;
  float4 v = *(const float4*)(in + i);
  ushort4 o;
  o.x = f2bf(v.x); o.y = f2bf(v.y); o.z = f2bf(v.z); o.w = f2bf(v.w);
  *(ushort4*)(out + i) = o;
}

// ---------------- fp32 [R][C] -> bf16 [C][R] transpose ----------------
__global__ __launch_bounds__(256) void transpose_f32_bf16(const float* __restrict__ in, u16* __restrict__ out, int R, int C){
  __shared__ u16 tile[32][33];
  int bc = blockIdx.x*32, br = blockIdx.y*32;
  int tx = threadIdx.x & 31, ty = threadIdx.x >> 5;
  #pragma unroll
  for (int i=ty;i<32;i+=8) tile[i][tx] = f2bf(in[(size_t)(br+i)*C + bc + tx]);
  __syncthreads();
  #pragma unroll
  for (int i=ty;i<32;i+=8) out[(size_t)(bc+i)*R + br + tx] = tile[tx][i];
}

// ---------------- GEMM: C[M][N] = A[M][K] @ Bt[N][K]^T + bias, BK=64, swizzled async staging ----------------
// LDS rows of 64 u16 store chunk c at phys c^(row&7); frag reads conflict-free.
template<int BN, typename OutT>
__global__ __launch_bounds__(256) void gemm_bt_bias(
    const u16* __restrict__ A, const u16* __restrict__ Bt,
    const float* __restrict__ bias, OutT* __restrict__ C,
    int M, int N, int K)
{
  __shared__ __align__(16) u16 As[128*64];
  __shared__ __align__(16) u16 Bs[BN*64];
  const int m0 = blockIdx.y*128, n0 = blockIdx.x*BN;
  const int tid = threadIdx.x, wave = tid>>6, lane = tid&63;
  const int wr = (wave>>1)*64, wc = (wave&1)*(BN/2);
  const int ml = lane&15, quad = lane>>4;
  const int lrow8 = lane>>3, lchk = lane&7;
  const int swzg = (lchk ^ lrow8)*8;
  const u16* gA[4]; u16* lA[4];
  #pragma unroll
  for (int t=0;t<4;t++){
    gA[t] = A + (size_t)(m0 + wave*32 + t*8 + lrow8)*K + swzg;
    lA[t] = &As[(wave*32 + t*8)*64];
  }
  constexpr int BI = BN/32;   // 8-row issues per wave
  const u16* gB[BI]; u16* lB[BI];
  #pragma unroll
  for (int t=0;t<BI;t++){
    gB[t] = Bt + (size_t)(n0 + wave*(BN/4) + t*8 + lrow8)*K + swzg;
    lB[t] = &Bs[(wave*(BN/4) + t*8)*64];
  }
  constexpr int NJ = BN/32;
  f32x4 acc[4][NJ] = {};
  const int rch0 = ( quad      ^ (ml&7))*8;  // k 0..31  (logical chunk quad)
  const int rch1 = ((quad|4) ^ (ml&7))*8;    // k 32..63 (logical chunk quad+4)
  for (int k0=0; k0<K; k0+=64) {
    #pragma unroll
    for (int t=0;t<4;t++)  async_cp16(gA[t]+k0, lA[t]);
    #pragma unroll
    for (int t=0;t<BI;t++) async_cp16(gB[t]+k0, lB[t]);
    __syncthreads();
    #pragma unroll
    for (int kk=0;kk<2;kk++){
      const int rc = kk ? rch1 : rch0;
      bf16x8 af[4], bfr[NJ];
      #pragma unroll
      for (int i=0;i<4;i++)  af[i]  = *(const bf16x8*)&As[(wr+i*16+ml)*64 + rc];
      #pragma unroll
      for (int j=0;j<NJ;j++) bfr[j] = *(const bf16x8*)&Bs[(wc+j*16+ml)*64 + rc];
      #pragma unroll
      for (int i=0;i<4;i++)
        #pragma unroll
        for (int j=0;j<NJ;j++)
          acc[i][j] = MFMA(af[i], bfr[j], acc[i][j]);
    }
    __syncthreads();
  }
  #pragma unroll
  for (int j=0;j<NJ;j++){
    int col = n0 + wc + j*16 + ml;
    float bv = bias[col];
    #pragma unroll
    for (int i=0;i<4;i++){
      int row0 = m0 + wr + i*16 + quad*4;
      #pragma unroll
      for (int r=0;r<4;r++){
        float val = acc[i][j][r] + bv;
        if constexpr (std::is_same_v<OutT, float>)
          C[(size_t)(row0+r)*N + col] = val;
        else
          C[(size_t)(row0+r)*N + col] = f2bf(val);
      }
    }
  }
}

// ---------------- fused RoPE + split + V-transpose(+key-permute) ----------------
// grid (128 tq, 16 h), 256 thr. Per block: 32 t x 64 d of one head.
// Q pre-scaled 0.125*log2e; K ropied; V passes through bit-exact into V^T
// [h][64][4096] with the within-32-key permutation (phys quad*8+b*4+r <- logical b*16+quad*4+r).
__global__ __launch_bounds__(256) void rope_split_vt(
    const u16* __restrict__ QKV, const float* __restrict__ cosb, const float* __restrict__ sinb,
    u16* __restrict__ Qo, u16* __restrict__ Ko, u16* __restrict__ VTo)
{
  __shared__ __align__(16) u16 vt[64*40];
  const int t0 = blockIdx.x*32, h = blockIdx.y;
  const int tid = threadIdx.x;
  const int tl = tid>>3, d8 = (tid&7)*8;
  const int t = t0 + tl;
  const u16* base = QKV + (size_t)t*3072 + h*64 + d8;
  uint4 qw = *(const uint4*)base;
  uint4 kw = *(const uint4*)(base + 1024);
  uint4 vw = *(const uint4*)(base + 2048);
  // partner half (d^32) lives in thread tid^4 (same wave)
  uint4 qp, kp;
  qp.x=__shfl_xor((int)qw.x,4,64); qp.y=__shfl_xor((int)qw.y,4,64);
  qp.z=__shfl_xor((int)qw.z,4,64); qp.w=__shfl_xor((int)qw.w,4,64);
  kp.x=__shfl_xor((int)kw.x,4,64); kp.y=__shfl_xor((int)kw.y,4,64);
  kp.z=__shfl_xor((int)kw.z,4,64); kp.w=__shfl_xor((int)kw.w,4,64);
  const float* cp = cosb + (size_t)t*64 + d8;
  const float* sp = sinb + (size_t)t*64 + d8;
  float4 c0 = *(const float4*)cp, c1 = *(const float4*)(cp+4);
  float4 s0 = *(const float4*)sp, s1 = *(const float4*)(sp+4);
  const float sgn = (d8<32) ? -1.f : 1.f;
  const unsigned* qwa = &qw.x; const unsigned* qpa = &qp.x;
  const unsigned* kwa = &kw.x; const unsigned* kpa = &kp.x;
  const float* ca = &c0.x; const float* sa = &s0.x; // c0..c1 contiguous? not guaranteed; index explicitly
  float cc[8] = {c0.x,c0.y,c0.z,c0.w,c1.x,c1.y,c1.z,c1.w};
  float ss[8] = {s0.x,s0.y,s0.z,s0.w,s1.x,s1.y,s1.z,s1.w};
  (void)ca; (void)sa;
  unsigned qout[4], kout[4];
  #pragma unroll
  for (int p=0;p<4;p++){
    u16 qa = (u16)(qwa[p]&0xffff), qb = (u16)(qwa[p]>>16);
    u16 pa = (u16)(qpa[p]&0xffff), pb = (u16)(qpa[p]>>16);
    float r0 = bf2f(qa)*cc[2*p]   + sgn*bf2f(pa)*ss[2*p];
    float r1 = bf2f(qb)*cc[2*p+1] + sgn*bf2f(pb)*ss[2*p+1];
    qout[p] = pkbf(r0*(0.125f*1.44269504f), r1*(0.125f*1.44269504f));
    u16 ka_ = (u16)(kwa[p]&0xffff), kb_ = (u16)(kwa[p]>>16);
    u16 pka = (u16)(kpa[p]&0xffff), pkb2 = (u16)(kpa[p]>>16);
    float k0_ = bf2f(ka_)*cc[2*p]   + sgn*bf2f(pka)*ss[2*p];
    float k1_ = bf2f(kb_)*cc[2*p+1] + sgn*bf2f(pkb2)*ss[2*p+1];
    kout[p] = pkbf(k0_, k1_);
  }
  size_t qkrow = ((size_t)h*4096 + t)*64 + d8;
  *(uint4*)&Qo[qkrow] = *(uint4*)qout;
  *(uint4*)&Ko[qkrow] = *(uint4*)kout;
  // V -> LDS transpose with key permutation (phys col tph holds logical t tl)
  const int tph = ((tl>>2)&3)*8 + ((tl>>4)&1)*4 + (tl&3);
  const unsigned* vwa = &vw.x;
  #pragma unroll
  for (int p=0;p<4;p++){
    vt[(d8+2*p  )*40 + tph] = (u16)(vwa[p]&0xffff);
    vt[(d8+2*p+1)*40 + tph] = (u16)(vwa[p]>>16);
  }
  __syncthreads();
  const int d_out = tid>>2, t8 = (tid&3)*8;
  uint4 w = *(const uint4*)&vt[d_out*40 + t8];
  *(uint4*)&VTo[((size_t)h*64 + d_out)*4096 + t0 + t8] = w;
}

// ---------------- flash attention: 64 q/wave, in-register P, K-split x4 ----------------
// grid (16 qt, 16 h, 4 ks); 4 waves x 64 q = 256 q/block; BK=64; 1024 keys per block.
// S^T = MFMA(A=K,B=Q), kb-outer shares kf across 4 q-subtiles; V^T pre-permuted so packed
// exp2(S^T) frags feed PV directly; row sums via ones-MFMA; partials exactly additive.
__global__ __launch_bounds__(256,2) void flash_attn(
    const u16* __restrict__ Q, const u16* __restrict__ Kg, const u16* __restrict__ VT,
    u16* __restrict__ O0, u16* __restrict__ O1, u16* __restrict__ O2, u16* __restrict__ O3,
    float* __restrict__ Lpart)
{
  constexpr int SEQ=4096, QTR=1024;
  __shared__ __align__(16) u16 Ks[64*64];
  __shared__ __align__(16) u16 Vs[64*64];
  const int qt=blockIdx.x, h=blockIdx.y, ks=blockIdx.z;
  const int tid=threadIdx.x, wave=tid>>6, lane=tid&63;
  const int ml=lane&15, quad=lane>>4;
  const int qbase = qt*256 + wave*64;
  bf16x8 qf[4][2];
  #pragma unroll
  for (int qi=0; qi<4; qi++){
    const u16* qp = Q + ((size_t)h*SEQ + qbase + qi*16 + ml)*64;
    qf[qi][0] = *(const bf16x8*)(qp + quad*8);
    qf[qi][1] = *(const bf16x8*)(qp + 32 + quad*8);
  }
  const bf16x8 ones = {0x3F80,0x3F80,0x3F80,0x3F80,0x3F80,0x3F80,0x3F80,0x3F80};
  f32x4 o[4][4] = {};
  f32x4 accsum[4] = {};
  const int lrow8 = lane>>3, lchk = lane&7;
  const int swzg = (lchk ^ lrow8)*8;
  const u16* kgl = Kg + (size_t)h*SEQ*64 + (size_t)(ks*QTR + wave*16 + lrow8)*64 + swzg;
  const u16* vgl = VT + (size_t)h*64*SEQ + (size_t)(wave*16 + lrow8)*SEQ + ks*QTR + swzg;
  u16* kl0 = &Ks[(wave*16  )*64];
  u16* kl1 = &Ks[(wave*16+8)*64];
  u16* vl0 = &Vs[(wave*16  )*64];
  u16* vl1 = &Vs[(wave*16+8)*64];
  const int swzA = ( quad     ^ (ml&7))*8;
  const int swzB = ((quad^4) ^ (ml&7))*8;

  for (int k0=0;k0<QTR;k0+=64) {
    async_cp16(kgl + (size_t)k0*64,       kl0);
    async_cp16(kgl + (size_t)k0*64 + 512, kl1);
    async_cp16(vgl + k0,                  vl0);
    async_cp16(vgl + 8*SEQ + k0,          vl1);
    __syncthreads();
    f32x4 s[4][4];
    #pragma unroll
    for (int kb=0;kb<4;kb++){
      bf16x8 kf0 = *(const bf16x8*)&Ks[(kb*16+ml)*64 + swzA];
      bf16x8 kf1 = *(const bf16x8*)&Ks[(kb*16+ml)*64 + swzB];
      #pragma unroll
      for (int qi=0;qi<4;qi++){
        f32x4 z = {0,0,0,0};
        z = MFMA(kf0, qf[qi][0], z);
        s[qi][kb] = MFMA(kf1, qf[qi][1], z);
      }
    }
    bf16x8 vf[4][2];
    #pragma unroll
    for (int db=0;db<4;db++){
      vf[db][0] = *(const bf16x8*)&Vs[(db*16+ml)*64 + swzA];
      vf[db][1] = *(const bf16x8*)&Vs[(db*16+ml)*64 + swzB];
    }
    #pragma unroll
    for (int qi=0; qi<4; qi++)
      #pragma unroll
      for (int p=0;p<2;p++){
        float e0 = EXP2(s[qi][2*p][0]),   e1 = EXP2(s[qi][2*p][1]);
        float e2 = EXP2(s[qi][2*p][2]),   e3 = EXP2(s[qi][2*p][3]);
        float e4 = EXP2(s[qi][2*p+1][0]), e5 = EXP2(s[qi][2*p+1][1]);
        float e6 = EXP2(s[qi][2*p+1][2]), e7 = EXP2(s[qi][2*p+1][3]);
        union { uint4 u; bf16x8 v; } pf;
        pf.u.x = pkbf(e0,e1); pf.u.y = pkbf(e2,e3);
        pf.u.z = pkbf(e4,e5); pf.u.w = pkbf(e6,e7);
        accsum[qi] = MFMA(ones, pf.v, accsum[qi]);
        #pragma unroll
        for (int db=0;db<4;db++)
          o[qi][db] = MFMA(vf[db][p], pf.v, o[qi][db]);
      }
    __syncthreads();
  }
  u16* op = (ks==0) ? O0 : (ks==1) ? O1 : (ks==2) ? O2 : O3;
  #pragma unroll
  for (int qi=0;qi<4;qi++){
    size_t rb = (size_t)(qbase + qi*16 + ml)*1024 + h*64;
    #pragma unroll
    for (int db=0;db<4;db++){
      uint2 w;
      w.x = pkbf(o[qi][db][0], o[qi][db][1]);
      w.y = pkbf(o[qi][db][2], o[qi][db][3]);
      *(uint2*)&op[rb + db*16 + quad*4] = w;
    }
  }
  if (quad==0){
    float* lp = Lpart + (size_t)ks*65536 + (size_t)h*4096 + qbase;
    #pragma unroll
    for (int qi=0;qi<4;qi++) lp[qi*16+ml] = accsum[qi][0];
  }
}

// ---------------- combine the four K-split partials, normalize, emit bf16 AO ----------------
__global__ __launch_bounds__(256) void combine_softmax4(
    const u16* __restrict__ O0, const u16* __restrict__ O1,
    const u16* __restrict__ O2, const u16* __restrict__ O3,
    const float* __restrict__ L, u16* __restrict__ AO)
{
  int i = (blockIdx.x*256 + threadIdx.x)*4;
  int row = i >> 10, col = i & 1023, h = col >> 6;
  int li = h*4096 + row;
  float inv = 1.f/(L[li] + L[li+65536] + L[li+2*65536] + L[li+3*65536]);
  ushort4 a = *(const ushort4*)(O0+i);
  ushort4 b = *(const ushort4*)(O1+i);
  ushort4 c = *(const ushort4*)(O2+i);
  ushort4 d = *(const ushort4*)(O3+i);
  ushort4 o;
  o.x = f2bf((bf2f(a.x)+bf2f(b.x)+bf2f(c.x)+bf2f(d.x))*inv);
  o.y = f2bf((bf2f(a.y)+bf2f(b.y)+bf2f(c.y)+bf2f(d.y))*inv);
  o.z = f2bf((bf2f(a.z)+bf2f(b.z)+bf2f(c.z)+bf2f(d.z))*inv);
  o.w = f2bf((bf2f(a.w)+bf2f(b.w)+bf2f(c.w)+bf2f(d.w))*inv);
  *(ushort4*)(AO+i) = o;
}

extern "C" void kernel_launch(void* const* d_in, const int* in_sizes, int n_in,
                              void* d_out, int out_size, void* d_ws, size_t ws_size,
                              hipStream_t stream)
{
  (void)in_sizes; (void)n_in; (void)out_size; (void)ws_size;
  const float* H     = (const float*)d_in[0];
  // d_in[1] = cu_seqlens (unused by reference)
  const float* cosb  = (const float*)d_in[2];
  const float* sinb  = (const float*)d_in[3];
  const float* Wqkv  = (const float*)d_in[4];
  const float* bqkv  = (const float*)d_in[5];
  const float* Wproj = (const float*)d_in[6];
  const float* bproj = (const float*)d_in[7];
  float* out = (float*)d_out;
  char* ws = (char*)d_ws;
  // 64 MiB budget; lifetimes: Hb dead after QKV gemm -> VTb; WqkvT dead after gemm -> Qb -> AO;
  // QKVr dead after rope_split_vt -> Opart0/1/2.
  float* Lpart  = (float*)(ws + 0);         // [4][16][4096] f32, 1 MB
  u16*   WprojT = (u16*)(ws + 2097152);     // 2 MB
  u16*   Hb     = (u16*)(ws + 4194304);     // 8 MB
  u16*   VTb    = (u16*)(ws + 4194304);     //   (reuses Hb) [16][64][4096] permuted
  u16*   QKVr   = (u16*)(ws + 12582912);    // 24 MB
  u16*   Opart0 = (u16*)(ws + 12582912);    //   (reuses QKVr)
  u16*   Opart1 = (u16*)(ws + 20971520);
  u16*   Opart2 = (u16*)(ws + 29360128);
  u16*   WqkvT  = (u16*)(ws + 37748736);    // 6 MB
  u16*   Qb     = (u16*)(ws + 37748736);    //   (reuses WqkvT) 8 MB
  u16*   AO     = (u16*)(ws + 37748736);    //   (reuses Qb)
  u16*   Kb     = (u16*)(ws + 46137344);    // 8 MB
  u16*   Opart3 = (u16*)(ws + 54525952);    // 8 MB  (ends 60 MB)

  hipLaunchKernelGGL(cvt_f32_bf16, dim3(4096), dim3(256), 0, stream, H, Hb, 4096*1024);
  hipLaunchKernelGGL(transpose_f32_bf16, dim3(96,32), dim3(256), 0, stream, Wqkv, WqkvT, 1024, 3072);
  hipLaunchKernelGGL(transpose_f32_bf16, dim3(32,32), dim3(256), 0, stream, Wproj, WprojT, 1024, 1024);
  hipLaunchKernelGGL((gemm_bt_bias<128,u16>), dim3(24,32), dim3(256), 0, stream, Hb, WqkvT, bqkv, QKVr, 4096, 3072, 1024);
  hipLaunchKernelGGL(rope_split_vt, dim3(128,16), dim3(256), 0, stream, QKVr, cosb, sinb, Qb, Kb, VTb);
  hipLaunchKernelGGL(flash_attn, dim3(16,16,4), dim3(256), 0, stream, Qb, Kb, VTb,
                     Opart0, Opart1, Opart2, Opart3, Lpart);
  hipLaunchKernelGGL(combine_softmax4, dim3(4096), dim3(256), 0, stream,
                     Opart0, Opart1, Opart2, Opart3, Lpart, AO);
  hipLaunchKernelGGL((gemm_bt_bias<64,float>), dim3(16,32), dim3(256), 0, stream, AO, WprojT, bproj, out, 4096, 1024, 1024);
}

// Round 9
// 251.842 us; speedup vs baseline: 1.0201x; 1.0201x over previous
//
#include <hip/hip_runtime.h>
#include <type_traits>

typedef short bf16x8 __attribute__((ext_vector_type(8)));
typedef float f32x4  __attribute__((ext_vector_type(4)));
typedef unsigned short u16;

#define MFMA(a,b,c) __builtin_amdgcn_mfma_f32_16x16x32_bf16((a),(b),(c),0,0,0)

__device__ __forceinline__ float bf2f(u16 u){ unsigned x=((unsigned)u)<<16; return __builtin_bit_cast(float,x); }
__device__ __forceinline__ u16 f2bf(float f){ unsigned x=__builtin_bit_cast(unsigned,f); x += 0x7fffu + ((x>>16)&1u); return (u16)(x>>16); }

#if __has_builtin(__builtin_amdgcn_cvt_pk_bf16_f32)
typedef __bf16 hwbf2 __attribute__((ext_vector_type(2)));
__device__ __forceinline__ unsigned pkbf(float a, float b){
  hwbf2 r = __builtin_amdgcn_cvt_pk_bf16_f32(a, b);   // lo=a, hi=b, RNE
  return __builtin_bit_cast(unsigned, r);
}
#else
__device__ __forceinline__ unsigned pkbf(float a, float b){
  unsigned ua = __builtin_bit_cast(unsigned, a), ub = __builtin_bit_cast(unsigned, b);
  ua += 0x7fffu + ((ua>>16)&1u);
  ub += 0x7fffu + ((ub>>16)&1u);
  return __builtin_amdgcn_perm(ub, ua, 0x07060302u);
}
#endif

#if __has_builtin(__builtin_amdgcn_exp2f)
#define EXP2(x) __builtin_amdgcn_exp2f(x)
#else
#define EXP2(x) exp2f(x)
#endif

__device__ __forceinline__ void async_cp16(const u16* g, u16* l){
  __builtin_amdgcn_global_load_lds((const __attribute__((address_space(1))) void*)g,
                                   (__attribute__((address_space(3))) void*)l, 16, 0, 0);
}

// ---------------- fused prep: cvt H->bf16, transpose Wqkv & Wproj to bf16 ----------------
// flat grid 8192: [0,4096) cvt; [4096,7168) Wqkv^T; [7168,8192) Wproj^T
__global__ __launch_bounds__(256) void prep(
    const float* __restrict__ H, const float* __restrict__ Wqkv, const float* __restrict__ Wproj,
    u16* __restrict__ Hb, u16* __restrict__ WqkvT, u16* __restrict__ WprojT)
{
  __shared__ u16 tile[32][33];
  const int bid = blockIdx.x, tid = threadIdx.x;
  if (bid < 4096) {
    int i = (bid*256 + tid)*4;
    float4 v = *(const float4*)(H + i);
    ushort4 o;
    o.x = f2bf(v.x); o.y = f2bf(v.y); o.z = f2bf(v.z); o.w = f2bf(v.w);
    *(ushort4*)(Hb + i) = o;
    return;
  }
  const float* in; u16* out; int R, C, bx, by;
  if (bid < 7168) { int t = bid-4096; in=Wqkv; out=WqkvT; R=1024; C=3072; bx=t%96; by=t/96; }
  else            { int t = bid-7168; in=Wproj; out=WprojT; R=1024; C=1024; bx=t%32; by=t/32; }
  int bc = bx*32, br = by*32;
  int tx = tid & 31, ty = tid >> 5;
  #pragma unroll
  for (int i=ty;i<32;i+=8) tile[i][tx] = f2bf(in[(size_t)(br+i)*C + bc + tx]);
  __syncthreads();
  #pragma unroll
  for (int i=ty;i<32;i+=8) out[(size_t)(bc+i)*R + br + tx] = tile[tx][i];
}

// ---------------- QKV GEMM with fused bias + RoPE + split epilogue ----------------
// C = Hb[4096][1024] @ WqkvT[3072][1024]^T + b; then RoPE(Q,K) and scatter to
// Qo/Ko [h][t][64] (Q pre-scaled 0.125*log2e) and Vo [h][t][64].
// RoPE partner d^32 = acc[i][j^2] same lane (wave covers one full head's 64 cols).
__global__ __launch_bounds__(256) void gemm_qkv_rope(
    const u16* __restrict__ A, const u16* __restrict__ Bt,
    const float* __restrict__ bias, const float* __restrict__ cosb, const float* __restrict__ sinb,
    u16* __restrict__ Qo, u16* __restrict__ Ko, u16* __restrict__ Vo)
{
  constexpr int K = 1024;
  __shared__ __align__(16) u16 As[128*64];
  __shared__ __align__(16) u16 Bs[128*64];
  const int m0 = blockIdx.y*128, n0 = blockIdx.x*128;
  const int tid = threadIdx.x, wave = tid>>6, lane = tid&63;
  const int wr = (wave>>1)*64, wc = (wave&1)*64;
  const int ml = lane&15, quad = lane>>4;
  const int lrow8 = lane>>3, lchk = lane&7;
  const int swzg = (lchk ^ lrow8)*8;
  const u16* gA[4]; u16* lA[4];
  const u16* gB[4]; u16* lB[4];
  #pragma unroll
  for (int t=0;t<4;t++){
    gA[t] = A  + (size_t)(m0 + wave*32 + t*8 + lrow8)*K + swzg;
    lA[t] = &As[(wave*32 + t*8)*64];
    gB[t] = Bt + (size_t)(n0 + wave*32 + t*8 + lrow8)*K + swzg;
    lB[t] = &Bs[(wave*32 + t*8)*64];
  }
  f32x4 acc[4][4] = {};
  const int rch0 = ( quad     ^ (ml&7))*8;
  const int rch1 = ((quad|4) ^ (ml&7))*8;
  for (int k0=0; k0<K; k0+=64) {
    #pragma unroll
    for (int t=0;t<4;t++){ async_cp16(gA[t]+k0, lA[t]); async_cp16(gB[t]+k0, lB[t]); }
    __syncthreads();
    #pragma unroll
    for (int kk=0;kk<2;kk++){
      const int rc = kk ? rch1 : rch0;
      bf16x8 af[4], bfr[4];
      #pragma unroll
      for (int i=0;i<4;i++)  af[i]  = *(const bf16x8*)&As[(wr+i*16+ml)*64 + rc];
      #pragma unroll
      for (int j=0;j<4;j++) bfr[j] = *(const bf16x8*)&Bs[(wc+j*16+ml)*64 + rc];
      #pragma unroll
      for (int i=0;i<4;i++)
        #pragma unroll
        for (int j=0;j<4;j++)
          acc[i][j] = MFMA(af[i], bfr[j], acc[i][j]);
    }
    __syncthreads();
  }
  const int region = n0 >> 10;   // 0=Q, 1=K, 2=V (block-uniform)
  if (region == 2) {
    #pragma unroll
    for (int j=0;j<4;j++){
      int col = n0 + wc + j*16 + ml;
      int dloc = col & 63, hh = (col & 1023) >> 6;
      float bv = bias[col];
      #pragma unroll
      for (int i=0;i<4;i++){
        int row0 = m0 + wr + i*16 + quad*4;
        #pragma unroll
        for (int r=0;r<4;r++)
          Vo[((size_t)hh*4096 + row0 + r)*64 + dloc] = f2bf(acc[i][j][r] + bv);
      }
    }
  } else {
    u16* dst = region ? Ko : Qo;
    const float qs = region ? 1.0f : 0.125f*1.44269504f;
    #pragma unroll
    for (int j=0;j<4;j++){
      int col = n0 + wc + j*16 + ml;
      int dloc = col & 63, hh = (col & 1023) >> 6;
      float bv  = bias[col];
      float bvp = bias[col ^ 32];
      float sgn = (dloc < 32) ? -1.f : 1.f;
      #pragma unroll
      for (int i=0;i<4;i++){
        int row0 = m0 + wr + i*16 + quad*4;
        #pragma unroll
        for (int r=0;r<4;r++){
          int t = row0 + r;
          float c = cosb[t*64 + dloc], s = sinb[t*64 + dloc];
          float val = acc[i][j][r]   + bv;
          float par = acc[i][j^2][r] + bvp;
          dst[((size_t)hh*4096 + t)*64 + dloc] = f2bf((val*c + sgn*par*s)*qs);
        }
      }
    }
  }
}

// ---------------- per-head bf16 transpose WITH key-permutation ----------------
// in [16][4096][64] -> out [16][64][4096]; within each 32-key group physical col
// quad*8+b*4+r holds logical key b*16+quad*4+r.
__global__ __launch_bounds__(256) void vtrans_perm_bf16(const u16* __restrict__ in, u16* __restrict__ out){
  __shared__ u16 tile[32][33];
  const int h = blockIdx.z;
  const u16* ip = in + (size_t)h*4096*64;
  u16* op = out + (size_t)h*64*4096;
  int bt = blockIdx.x*32, bd = blockIdx.y*32;
  int tx = threadIdx.x & 31, ty = threadIdx.x >> 5;
  #pragma unroll
  for (int i=ty;i<32;i+=8) tile[i][tx] = ip[(size_t)(bt+i)*64 + bd + tx];
  __syncthreads();
  const int tlog = ((tx>>2)&1)*16 + (tx>>3)*4 + (tx&3);
  #pragma unroll
  for (int i=ty;i<32;i+=8) op[(size_t)(bd+i)*4096 + bt + tx] = tile[tlog][i];
}

// ---------------- generic GEMM (proj): C[M][N] = A @ Bt^T + bias ----------------
template<int BN, typename OutT>
__global__ __launch_bounds__(256) void gemm_bt_bias(
    const u16* __restrict__ A, const u16* __restrict__ Bt,
    const float* __restrict__ bias, OutT* __restrict__ C,
    int M, int N, int K)
{
  __shared__ __align__(16) u16 As[128*64];
  __shared__ __align__(16) u16 Bs[BN*64];
  const int m0 = blockIdx.y*128, n0 = blockIdx.x*BN;
  const int tid = threadIdx.x, wave = tid>>6, lane = tid&63;
  const int wr = (wave>>1)*64, wc = (wave&1)*(BN/2);
  const int ml = lane&15, quad = lane>>4;
  const int lrow8 = lane>>3, lchk = lane&7;
  const int swzg = (lchk ^ lrow8)*8;
  const u16* gA[4]; u16* lA[4];
  #pragma unroll
  for (int t=0;t<4;t++){
    gA[t] = A + (size_t)(m0 + wave*32 + t*8 + lrow8)*K + swzg;
    lA[t] = &As[(wave*32 + t*8)*64];
  }
  constexpr int BI = BN/32;
  const u16* gB[BI]; u16* lB[BI];
  #pragma unroll
  for (int t=0;t<BI;t++){
    gB[t] = Bt + (size_t)(n0 + wave*(BN/4) + t*8 + lrow8)*K + swzg;
    lB[t] = &Bs[(wave*(BN/4) + t*8)*64];
  }
  constexpr int NJ = BN/32;
  f32x4 acc[4][NJ] = {};
  const int rch0 = ( quad     ^ (ml&7))*8;
  const int rch1 = ((quad|4) ^ (ml&7))*8;
  for (int k0=0; k0<K; k0+=64) {
    #pragma unroll
    for (int t=0;t<4;t++)  async_cp16(gA[t]+k0, lA[t]);
    #pragma unroll
    for (int t=0;t<BI;t++) async_cp16(gB[t]+k0, lB[t]);
    __syncthreads();
    #pragma unroll
    for (int kk=0;kk<2;kk++){
      const int rc = kk ? rch1 : rch0;
      bf16x8 af[4], bfr[NJ];
      #pragma unroll
      for (int i=0;i<4;i++)  af[i]  = *(const bf16x8*)&As[(wr+i*16+ml)*64 + rc];
      #pragma unroll
      for (int j=0;j<NJ;j++) bfr[j] = *(const bf16x8*)&Bs[(wc+j*16+ml)*64 + rc];
      #pragma unroll
      for (int i=0;i<4;i++)
        #pragma unroll
        for (int j=0;j<NJ;j++)
          acc[i][j] = MFMA(af[i], bfr[j], acc[i][j]);
    }
    __syncthreads();
  }
  #pragma unroll
  for (int j=0;j<NJ;j++){
    int col = n0 + wc + j*16 + ml;
    float bv = bias[col];
    #pragma unroll
    for (int i=0;i<4;i++){
      int row0 = m0 + wr + i*16 + quad*4;
      #pragma unroll
      for (int r=0;r<4;r++){
        float val = acc[i][j][r] + bv;
        if constexpr (std::is_same_v<OutT, float>)
          C[(size_t)(row0+r)*N + col] = val;
        else
          C[(size_t)(row0+r)*N + col] = f2bf(val);
      }
    }
  }
}

// ---------------- flash attention (r7 structure): 32 q/wave, in-register P, K-split x4 ----------------
__global__ __launch_bounds__(256,4) void flash_attn(
    const u16* __restrict__ Q, const u16* __restrict__ Kg, const u16* __restrict__ VT,
    u16* __restrict__ O0, u16* __restrict__ O1, u16* __restrict__ O2, u16* __restrict__ O3,
    float* __restrict__ Lpart)
{
  constexpr int SEQ=4096, QTR=1024;
  __shared__ __align__(16) u16 Ks[64*64];
  __shared__ __align__(16) u16 Vs[64*64];
  const int qt=blockIdx.x, h=blockIdx.y, ks=blockIdx.z;
  const int tid=threadIdx.x, wave=tid>>6, lane=tid&63;
  const int ml=lane&15, quad=lane>>4;
  const int qbase = qt*128 + wave*32;
  bf16x8 qf[2][2];
  #pragma unroll
  for (int qi=0; qi<2; qi++){
    const u16* qp = Q + ((size_t)h*SEQ + qbase + qi*16 + ml)*64;
    qf[qi][0] = *(const bf16x8*)(qp + quad*8);
    qf[qi][1] = *(const bf16x8*)(qp + 32 + quad*8);
  }
  const bf16x8 ones = {0x3F80,0x3F80,0x3F80,0x3F80,0x3F80,0x3F80,0x3F80,0x3F80};
  f32x4 o[2][4] = {};
  f32x4 accsum[2] = {};
  const int lrow8 = lane>>3, lchk = lane&7;
  const int swzg = (lchk ^ lrow8)*8;
  const u16* kgl = Kg + (size_t)h*SEQ*64 + (size_t)(ks*QTR + wave*16 + lrow8)*64 + swzg;
  const u16* vgl = VT + (size_t)h*64*SEQ + (size_t)(wave*16 + lrow8)*SEQ + ks*QTR + swzg;
  u16* kl0 = &Ks[(wave*16  )*64];
  u16* kl1 = &Ks[(wave*16+8)*64];
  u16* vl0 = &Vs[(wave*16  )*64];
  u16* vl1 = &Vs[(wave*16+8)*64];
  const int swzA = ( quad     ^ (ml&7))*8;
  const int swzB = ((quad^4) ^ (ml&7))*8;

  for (int k0=0;k0<QTR;k0+=64) {
    async_cp16(kgl + (size_t)k0*64,       kl0);
    async_cp16(kgl + (size_t)k0*64 + 512, kl1);
    async_cp16(vgl + k0,                  vl0);
    async_cp16(vgl + 8*SEQ + k0,          vl1);
    __syncthreads();
    f32x4 s[2][4];
    #pragma unroll
    for (int kb=0;kb<4;kb++){
      bf16x8 kf0 = *(const bf16x8*)&Ks[(kb*16+ml)*64 + swzA];
      bf16x8 kf1 = *(const bf16x8*)&Ks[(kb*16+ml)*64 + swzB];
      f32x4 z0={0,0,0,0}, z1={0,0,0,0};
      z0 = MFMA(kf0, qf[0][0], z0); s[0][kb] = MFMA(kf1, qf[0][1], z0);
      z1 = MFMA(kf0, qf[1][0], z1); s[1][kb] = MFMA(kf1, qf[1][1], z1);
    }
    bf16x8 vf[4][2];
    #pragma unroll
    for (int db=0;db<4;db++){
      vf[db][0] = *(const bf16x8*)&Vs[(db*16+ml)*64 + swzA];
      vf[db][1] = *(const bf16x8*)&Vs[(db*16+ml)*64 + swzB];
    }
    #pragma unroll
    for (int qi=0; qi<2; qi++)
      #pragma unroll
      for (int p=0;p<2;p++){
        float e0 = EXP2(s[qi][2*p][0]),   e1 = EXP2(s[qi][2*p][1]);
        float e2 = EXP2(s[qi][2*p][2]),   e3 = EXP2(s[qi][2*p][3]);
        float e4 = EXP2(s[qi][2*p+1][0]), e5 = EXP2(s[qi][2*p+1][1]);
        float e6 = EXP2(s[qi][2*p+1][2]), e7 = EXP2(s[qi][2*p+1][3]);
        union { uint4 u; bf16x8 v; } pf;
        pf.u.x = pkbf(e0,e1); pf.u.y = pkbf(e2,e3);
        pf.u.z = pkbf(e4,e5); pf.u.w = pkbf(e6,e7);
        accsum[qi] = MFMA(ones, pf.v, accsum[qi]);
        #pragma unroll
        for (int db=0;db<4;db++)
          o[qi][db] = MFMA(vf[db][p], pf.v, o[qi][db]);
      }
    __syncthreads();
  }
  u16* op = (ks==0) ? O0 : (ks==1) ? O1 : (ks==2) ? O2 : O3;
  #pragma unroll
  for (int qi=0;qi<2;qi++){
    size_t rb = (size_t)(qbase + qi*16 + ml)*1024 + h*64;
    #pragma unroll
    for (int db=0;db<4;db++){
      uint2 w;
      w.x = pkbf(o[qi][db][0], o[qi][db][1]);
      w.y = pkbf(o[qi][db][2], o[qi][db][3]);
      *(uint2*)&op[rb + db*16 + quad*4] = w;
    }
  }
  if (quad==0){
    float* lp = Lpart + (size_t)ks*65536 + (size_t)h*4096 + qbase;
    lp[ml]    = accsum[0][0];
    lp[16+ml] = accsum[1][0];
  }
}

// ---------------- combine the four K-split partials, normalize, emit bf16 AO ----------------
__global__ __launch_bounds__(256) void combine_softmax4(
    const u16* __restrict__ O0, const u16* __restrict__ O1,
    const u16* __restrict__ O2, const u16* __restrict__ O3,
    const float* __restrict__ L, u16* __restrict__ AO)
{
  int i = (blockIdx.x*256 + threadIdx.x)*4;
  int row = i >> 10, col = i & 1023, h = col >> 6;
  int li = h*4096 + row;
  float inv = 1.f/(L[li] + L[li+65536] + L[li+2*65536] + L[li+3*65536]);
  ushort4 a = *(const ushort4*)(O0+i);
  ushort4 b = *(const ushort4*)(O1+i);
  ushort4 c = *(const ushort4*)(O2+i);
  ushort4 d = *(const ushort4*)(O3+i);
  ushort4 o;
  o.x = f2bf((bf2f(a.x)+bf2f(b.x)+bf2f(c.x)+bf2f(d.x))*inv);
  o.y = f2bf((bf2f(a.y)+bf2f(b.y)+bf2f(c.y)+bf2f(d.y))*inv);
  o.z = f2bf((bf2f(a.z)+bf2f(b.z)+bf2f(c.z)+bf2f(d.z))*inv);
  o.w = f2bf((bf2f(a.w)+bf2f(b.w)+bf2f(c.w)+bf2f(d.w))*inv);
  *(ushort4*)(AO+i) = o;
}

extern "C" void kernel_launch(void* const* d_in, const int* in_sizes, int n_in,
                              void* d_out, int out_size, void* d_ws, size_t ws_size,
                              hipStream_t stream)
{
  (void)in_sizes; (void)n_in; (void)out_size; (void)ws_size;
  const float* H     = (const float*)d_in[0];
  // d_in[1] = cu_seqlens (unused by reference)
  const float* cosb  = (const float*)d_in[2];
  const float* sinb  = (const float*)d_in[3];
  const float* Wqkv  = (const float*)d_in[4];
  const float* bqkv  = (const float*)d_in[5];
  const float* Wproj = (const float*)d_in[6];
  const float* bproj = (const float*)d_in[7];
  float* out = (float*)d_out;
  char* ws = (char*)d_ws;
  // 60 MiB layout; lifetimes: Hb dead after gemm_qkv_rope -> VTb; Qb dead after flash -> AO;
  // Vb dead after vtrans -> Opart3; WqkvT dead after gemm -> Opart0.
  float* Lpart  = (float*)(ws + 0);         // [4][16][4096] f32, 1 MB
  u16*   WprojT = (u16*)(ws + 2097152);     // 2 MB
  u16*   Hb     = (u16*)(ws + 4194304);     // 8 MB
  u16*   VTb    = (u16*)(ws + 4194304);     //   (reuses Hb)
  u16*   Qb     = (u16*)(ws + 12582912);    // 8 MB
  u16*   AO     = (u16*)(ws + 12582912);    //   (reuses Qb)
  u16*   Kb     = (u16*)(ws + 20971520);    // 8 MB
  u16*   Vb     = (u16*)(ws + 29360128);    // 8 MB
  u16*   Opart3 = (u16*)(ws + 29360128);    //   (reuses Vb)
  u16*   WqkvT  = (u16*)(ws + 37748736);    // 6 MB
  u16*   Opart0 = (u16*)(ws + 37748736);    //   (reuses WqkvT) 8 MB
  u16*   Opart1 = (u16*)(ws + 46137344);    // 8 MB
  u16*   Opart2 = (u16*)(ws + 54525952);    // 8 MB (ends 60 MB)

  hipLaunchKernelGGL(prep, dim3(8192), dim3(256), 0, stream, H, Wqkv, Wproj, Hb, WqkvT, WprojT);
  hipLaunchKernelGGL(gemm_qkv_rope, dim3(24,32), dim3(256), 0, stream,
                     Hb, WqkvT, bqkv, cosb, sinb, Qb, Kb, Vb);
  hipLaunchKernelGGL(vtrans_perm_bf16, dim3(128,2,16), dim3(256), 0, stream, Vb, VTb);
  hipLaunchKernelGGL(flash_attn, dim3(32,16,4), dim3(256), 0, stream, Qb, Kb, VTb,
                     Opart0, Opart1, Opart2, Opart3, Lpart);
  hipLaunchKernelGGL(combine_softmax4, dim3(4096), dim3(256), 0, stream,
                     Opart0, Opart1, Opart2, Opart3, Lpart, AO);
  hipLaunchKernelGGL((gemm_bt_bias<64,float>), dim3(16,32), dim3(256), 0, stream,
                     AO, WprojT, bproj, out, 4096, 1024, 1024);
}